// Round 11
// baseline (331.451 us; speedup 1.0000x reference)
//
#include <hip/hip_runtime.h>

typedef __attribute__((ext_vector_type(8))) short bf16x8;
typedef __attribute__((ext_vector_type(4))) float f32x4;
typedef __attribute__((ext_vector_type(2))) float f32x2;
typedef __attribute__((ext_vector_type(4))) unsigned int u32x4;
typedef __attribute__((ext_vector_type(2))) unsigned int u32x2;

__device__ __forceinline__ unsigned short f2bf(float f) {
    union { float f; unsigned int u; } v; v.f = f;
    return (unsigned short)((v.u + 0x7fffu + ((v.u >> 16) & 1u)) >> 16);
}
__device__ __forceinline__ float bflo(unsigned int u) {
    union { unsigned int u; float f; } v; v.u = u << 16; return v.f;
}
__device__ __forceinline__ float bfhi(unsigned int u) {
    union { unsigned int u; float f; } v; v.u = u & 0xffff0000u; return v.f;
}
__device__ __forceinline__ f32x2 bfpair(unsigned int u) {
    union { unsigned int u; float f; } lo, hi;
    lo.u = u << 16; hi.u = u & 0xffff0000u;
    return (f32x2){lo.f, hi.f};
}

// bf16 DFT-8 twiddles, branchless.
// costab(m) = bf16(cos(2*pi*m/8)), nsintab(m) = bf16(-sin(2*pi*m/8))
__device__ __forceinline__ unsigned short costab(int m) {
    unsigned short mag = (m & 1) ? 0x3F35 : (((m & 3) == 0) ? 0x3F80 : 0);
    return mag | (((m >= 3) && (m <= 5)) ? 0x8000 : 0);
}
__device__ __forceinline__ unsigned short nsintab(int m) {
    unsigned short mag = (m & 1) ? 0x3F35 : (((m & 3) == 2) ? 0x3F80 : 0);
    return mag | (((m >= 1) && (m <= 3)) ? 0x8000 : 0);
}
// F-fragment for MFMA B-operand, computed in registers (no LDS F table).
// Elements t = cch*8 + j, j=0..7 of DFT row fcol: m = (fcol>>3)*cch + (fcol&7)*j mod 8.
__device__ __forceinline__ bf16x8 ffrag(int fcol, int cch, bool im) {
    const int base = ((fcol >> 3) * cch) & 7;
    const int step = fcol & 7;
    union { unsigned int u[4]; bf16x8 v; } cv;
    #pragma unroll
    for (int d = 0; d < 4; ++d) {
        int m0 = (base + step * (2 * d)) & 7;
        int m1 = (base + step * (2 * d + 1)) & 7;
        unsigned short t0 = im ? nsintab(m0) : costab(m0);
        unsigned short t1 = im ? nsintab(m1) : costab(m1);
        cv.u[d] = (unsigned int)t0 | ((unsigned int)t1 << 16);
    }
    return cv.v;
}

// gfx9 64-lane all-sum via DPP (VALU pipe, not LDS pipe).
__device__ __forceinline__ float wred_allsum(float x) {
    asm volatile(
        "s_nop 1\n\t"
        "v_add_f32_dpp %0, %0, %0 row_shr:1 bound_ctrl:0\n\t"
        "s_nop 1\n\t"
        "v_add_f32_dpp %0, %0, %0 row_shr:2 bound_ctrl:0\n\t"
        "s_nop 1\n\t"
        "v_add_f32_dpp %0, %0, %0 row_shr:4 bound_ctrl:0\n\t"
        "s_nop 1\n\t"
        "v_add_f32_dpp %0, %0, %0 row_shr:8 bound_ctrl:0\n\t"
        "s_nop 1\n\t"
        "v_add_f32_dpp %0, %0, %0 row_bcast:15 row_mask:0xa bound_ctrl:0\n\t"
        "s_nop 1\n\t"
        "v_add_f32_dpp %0, %0, %0 row_bcast:31 row_mask:0xc bound_ctrl:0\n\t"
        "s_nop 1"
        : "+v"(x));
    return __builtin_bit_cast(float, __builtin_amdgcn_readlane(__builtin_bit_cast(int, x), 63));
}

// ---------------------------------------------------------------------------
// K1: channel LayerNorm, NCHW fp32 -> NHWC bf16, via LDS transpose.
// Stats via quad-shuffle (part = tid&3) — no ps/ps2 round trip.
// ---------------------------------------------------------------------------
__global__ __launch_bounds__(256, 8)
void ln_kernel(const float* __restrict__ x, const float* __restrict__ evt,
               const float* __restrict__ lwx, const float* __restrict__ lbx,
               const float* __restrict__ lwe, const float* __restrict__ lbe,
               unsigned short* __restrict__ xo, unsigned short* __restrict__ eo)
{
    __shared__ float xt[64][68];
    __shared__ float smu[64], sinv[64], slw[64], slb[64];

    const int tid = threadIdx.x;
    const int z = blockIdx.z, b = blockIdx.y;
    const int hw0 = blockIdx.x * 64;
    const float* src = z ? evt : x;
    const float* lw  = z ? lwe : lwx;
    const float* lb  = z ? lbe : lbx;
    unsigned short* dst = z ? eo : xo;

    if (tid < 64) { slw[tid] = lw[tid]; slb[tid] = lb[tid]; }

    const float* sp = src + (size_t)b * 64 * 65536 + hw0;
    #pragma unroll
    for (int it = 0; it < 4; ++it) {
        int i = tid + it * 256;
        int c = i >> 4, p4 = i & 15;
        f32x4 v = *(const f32x4*)&sp[(size_t)c * 65536 + p4 * 4];
        xt[p4 * 4 + 0][c] = v.x;
        xt[p4 * 4 + 1][c] = v.y;
        xt[p4 * 4 + 2][c] = v.z;
        xt[p4 * 4 + 3][c] = v.w;
    }
    __syncthreads();

    {   // stats: 4 adjacent lanes per pixel, quad shuffle-reduce
        int px = tid >> 2, part = tid & 3;
        float s = 0.f, s2 = 0.f;
        #pragma unroll
        for (int j = 0; j < 4; ++j) {
            f32x4 v = *(const f32x4*)&xt[px][part * 16 + j * 4];
            s  += v.x + v.y + v.z + v.w;
            s2 += v.x * v.x + v.y * v.y + v.z * v.z + v.w * v.w;
        }
        s  += __shfl_xor(s, 1);  s  += __shfl_xor(s, 2);
        s2 += __shfl_xor(s2, 1); s2 += __shfl_xor(s2, 2);
        if (part == 0) {
            float mu = s * (1.f / 64.f);
            smu[px] = mu;
            sinv[px] = rsqrtf(s2 * (1.f / 64.f) - mu * mu + 1e-5f);
        }
    }
    __syncthreads();

    unsigned short* dp = dst + ((size_t)b * 65536 + hw0) * 64;
    #pragma unroll
    for (int it = 0; it < 2; ++it) {
        int i = tid + it * 256;
        int px = i >> 3, oct = i & 7;
        float mu = smu[px], inv = sinv[px];
        f32x4 v0 = *(const f32x4*)&xt[px][oct * 8];
        f32x4 v1 = *(const f32x4*)&xt[px][oct * 8 + 4];
        u32x4 w;
        int c = oct * 8;
        float a0 = (v0.x - mu) * inv * slw[c + 0] + slb[c + 0];
        float a1 = (v0.y - mu) * inv * slw[c + 1] + slb[c + 1];
        w[0] = (unsigned int)f2bf(a0) | ((unsigned int)f2bf(a1) << 16);
        a0 = (v0.z - mu) * inv * slw[c + 2] + slb[c + 2];
        a1 = (v0.w - mu) * inv * slw[c + 3] + slb[c + 3];
        w[1] = (unsigned int)f2bf(a0) | ((unsigned int)f2bf(a1) << 16);
        a0 = (v1.x - mu) * inv * slw[c + 4] + slb[c + 4];
        a1 = (v1.y - mu) * inv * slw[c + 5] + slb[c + 5];
        w[2] = (unsigned int)f2bf(a0) | ((unsigned int)f2bf(a1) << 16);
        a0 = (v1.z - mu) * inv * slw[c + 6] + slb[c + 6];
        a1 = (v1.w - mu) * inv * slw[c + 7] + slb[c + 7];
        w[3] = (unsigned int)f2bf(a0) | ((unsigned int)f2bf(a1) << 16);
        *(u32x4*)&dp[(size_t)px * 64 + oct * 8] = w;
    }
}

// ---------------------------------------------------------------------------
// K2: producer: conv1x1 (MFMA bf16, 128 out) + depthwise 3x3 + transposed
// blob store. Blob per patch: row c (64 bf16 = the 64 pixels, t-order),
// logical 8-px chunk s stored at slot s ^ (c & 7).  (R10-proven, frozen)
// ---------------------------------------------------------------------------
#define PR_WB    14336
#define PR_WDW   30720
#define PR_SMEM  35328

__global__ __launch_bounds__(512, 8)
void prod_kernel(const unsigned short* __restrict__ src,
                 const float* __restrict__ wmat, const float* __restrict__ wdw,
                 unsigned short* __restrict__ dst)
{
    __shared__ __align__(16) char smem[PR_SMEM];
    unsigned short* A   = (unsigned short*)(smem);
    unsigned short* Wb  = (unsigned short*)(smem + PR_WB);
    unsigned short* pre = (unsigned short*)(smem);          // overlays A+Wb
    float* swdw = (float*)(smem + PR_WDW);

    const int tid = threadIdx.x;
    const int pj = blockIdx.x, pi = blockIdx.y, b = blockIdx.z;
    const int h0 = pi * 8, w0 = pj * 8;

    #pragma unroll
    for (int it = 0; it < 4; ++it) {
        int i = tid + it * 512;
        int o = i >> 4, c4 = i & 15;
        f32x4 wv = *(const f32x4*)&wmat[o * 64 + c4 * 4];
        unsigned int lo = (unsigned int)f2bf(wv[0]) | ((unsigned int)f2bf(wv[1]) << 16);
        unsigned int hi = (unsigned int)f2bf(wv[2]) | ((unsigned int)f2bf(wv[3]) << 16);
        u32x2 pk = {lo, hi};
        *(u32x2*)&Wb[o * 64 + (((c4 >> 1) ^ (o & 7)) << 3) + (c4 & 1) * 4] = pk;
    }
    for (int i = tid; i < 1152; i += 512) swdw[i] = wdw[i];
    for (int i = tid; i < 768; i += 512) A[6400 + i] = 0;
    #pragma unroll
    for (int it = 0; it < 2; ++it) {
        int i = tid + it * 512;
        if (i < 800) {
            int px = i >> 3, oct = i & 7;
            int r = px / 10, cc = px - r * 10;
            int gh = h0 - 1 + r, gw = w0 - 1 + cc;
            u32x4 val = {0u, 0u, 0u, 0u};
            if (gh >= 0 && gh < 256 && gw >= 0 && gw < 256)
                val = *(const u32x4*)&src[((size_t)(b * 65536 + gh * 256 + gw)) * 64 + oct * 8];
            *(u32x4*)&A[px * 64 + ((oct ^ (px & 7)) << 3)] = val;
        }
    }
    __syncthreads();

    const int lane = tid & 63;
    const int l15 = lane & 15, l4 = lane >> 4;
    const int o_n = (tid >> 6) * 16 + l15;
    f32x4 acc[7];
    #pragma unroll
    for (int mt = 0; mt < 7; ++mt) acc[mt] = (f32x4){0.f, 0.f, 0.f, 0.f};
    #pragma unroll
    for (int ks = 0; ks < 2; ++ks) {
        int cch = ks * 4 + l4;
        bf16x8 bfrag = *(const bf16x8*)&Wb[o_n * 64 + ((cch ^ (o_n & 7)) << 3)];
        #pragma unroll
        for (int mt = 0; mt < 7; ++mt) {
            int px = mt * 16 + l15;
            bf16x8 afrag = *(const bf16x8*)&A[px * 64 + ((cch ^ (px & 7)) << 3)];
            acc[mt] = __builtin_amdgcn_mfma_f32_16x16x32_bf16(afrag, bfrag, acc[mt], 0, 0, 0);
        }
    }
    __syncthreads();

    #pragma unroll
    for (int mt = 0; mt < 7; ++mt)
        #pragma unroll
        for (int r = 0; r < 4; ++r) {
            int px = mt * 16 + l4 * 4 + r;
            if (px < 100)
                pre[px * 128 + (((o_n >> 3) ^ (px & 7)) << 3) + (o_n & 7)] = f2bf(acc[mt][r]);
        }
    __syncthreads();

    f32x2 res[8];
    {
        const int o = (tid & 63) * 2;
        const int och = o >> 3, osub = o & 7;
        const int pc = tid >> 6;
        f32x2 wdp[9];
        #pragma unroll
        for (int t = 0; t < 9; ++t)
            wdp[t] = (f32x2){swdw[o * 9 + t], swdw[o * 9 + 9 + t]};

        f32x2 ra[3], rb[3], rc[3];
        #define LOADROW(dstv, rr)                                                        \
            {                                                                            \
                _Pragma("unroll")                                                        \
                for (int d = 0; d < 3; ++d) {                                            \
                    int hp = (rr) * 10 + pc + d;                                         \
                    unsigned int u = *(const unsigned int*)                              \
                        &pre[hp * 128 + ((och ^ (hp & 7)) << 3) + osub];                 \
                    dstv[d] = bfpair(u);                                                 \
                }                                                                        \
            }
        LOADROW(ra, 0)
        LOADROW(rb, 1)
        #pragma unroll
        for (int r = 2; r < 10; ++r) {
            LOADROW(rc, r)
            f32x2 s = ra[0] * wdp[0];
            s += ra[1] * wdp[1]; s += ra[2] * wdp[2];
            s += rb[0] * wdp[3]; s += rb[1] * wdp[4]; s += rb[2] * wdp[5];
            s += rc[0] * wdp[6]; s += rc[1] * wdp[7]; s += rc[2] * wdp[8];
            res[r - 2] = s;
            #pragma unroll
            for (int d = 0; d < 3; ++d) { ra[d] = rb[d]; rb[d] = rc[d]; }
        }
        #undef LOADROW
    }
    __syncthreads();   // pre reads done -> ldout may overlay

    {
        unsigned short* ldout = (unsigned short*)smem;
        const int o = (tid & 63) * 2;
        const int pc = tid >> 6;
        const int key = pc << 4;
        #pragma unroll
        for (int r = 0; r < 8; ++r) {
            int px = r * 8 + pc;
            unsigned int pk = (unsigned int)f2bf(res[r].x) | ((unsigned int)f2bf(res[r].y) << 16);
            *(unsigned int*)&ldout[px * 128 + (o ^ key)] = pk;
        }
    }
    __syncthreads();

    // transposed store; blob slot key = c & 7 (matches MFMA A-fragment reads)
    {
        unsigned short* ldout = (unsigned short*)smem;
        const int c0 = (tid & 63) * 2;
        const int s = tid >> 6;
        const int sl0 = s ^ (c0 & 7);
        const int sl1 = s ^ ((c0 + 1) & 7);
        const size_t patchbase = ((size_t)(b * 32 + pi) * 32 + pj) * 8192;
        unsigned int rv[8];
        #pragma unroll
        for (int j = 0; j < 8; ++j)
            rv[j] = *(const unsigned int*)&ldout[(8 * s + j) * 128 + (c0 ^ (j << 4))];
        u32x4 lo, hi;
        #pragma unroll
        for (int d = 0; d < 4; ++d) {
            lo[d] = (rv[2 * d] & 0xffffu) | (rv[2 * d + 1] << 16);
            hi[d] = (rv[2 * d] >> 16) | (rv[2 * d + 1] & 0xffff0000u);
        }
        *(u32x4*)&dst[patchbase + (size_t)c0 * 64 + sl0 * 8]       = lo;
        *(u32x4*)&dst[patchbase + (size_t)(c0 + 1) * 64 + sl1 * 8] = hi;
    }
}

// ---------------------------------------------------------------------------
// K3: patch kernel — MFMA-DFT circular conv; F fragments computed in regs
// (forward B-frags == inverse B-frags since prow == fcol, F symmetric).
// LDS 49KB -> 3 blocks/CU.
// ---------------------------------------------------------------------------
#define PK_R0   0
#define PK_R1   16384
#define PK_WP   32768
#define PK_LW   49152
#define PK_LB   49664
#define PK_SMEM 50176

__global__ __launch_bounds__(512, 6)
void patch_kernel(const unsigned short* __restrict__ qb,
                  const unsigned short* __restrict__ kb,
                  const unsigned short* __restrict__ vb,
                  const float* __restrict__ w_proj,
                  const float* __restrict__ lnw, const float* __restrict__ lnb,
                  float* __restrict__ out)
{
    __shared__ __align__(16) char smem[PK_SMEM];
    unsigned short* sqT  = (unsigned short*)(smem + PK_R0);
    unsigned short* skT  = (unsigned short*)(smem + PK_R1);
    unsigned short* ohr  = sqT;                      // overlay AFTER barrier
    unsigned short* ohi  = skT;
    float*          out2 = (float*)smem;             // [64p][128c] xor-swizzled
    unsigned short* swp  = (unsigned short*)(smem + PK_WP);
    unsigned short* sy   = (unsigned short*)(smem + PK_R1);  // over out2hi
    float*          sc   = (float*)(smem + PK_R0);           // over out2lo
    float* slw = (float*)(smem + PK_LW);
    float* slb = (float*)(smem + PK_LB);

    const int tid = threadIdx.x;
    const int tj = blockIdx.x, ti = blockIdx.y, b = blockIdx.z;
    const int h0 = ti * 8, w0 = tj * 8;
    const size_t pbase = ((size_t)(b * 32 + ti) * 32 + tj) * 8192;

    const int pr = tid >> 6;
    const int cq = tid & 63;

    // v prefetch from transposed blob (logical chunk pr of rows 2cq, 2cq+1)
    u32x4 vreg0 = *(const u32x4*)&vb[pbase + (2 * cq) * 64 + ((pr ^ ((2 * cq) & 7)) << 3)];
    u32x4 vreg1 = *(const u32x4*)&vb[pbase + (2 * cq + 1) * 64 + ((pr ^ ((2 * cq + 1) & 7)) << 3)];

    if (tid < 128) { slw[tid] = lnw[tid]; slb[tid] = lnb[tid]; }
    #pragma unroll
    for (int it = 0; it < 2; ++it) {
        int i = tid + it * 512;
        *(u32x4*)&sqT[i * 8] = *(const u32x4*)&qb[pbase + i * 8];
        *(u32x4*)&skT[i * 8] = *(const u32x4*)&kb[pbase + i * 8];
    }
    #pragma unroll
    for (int it = 0; it < 4; ++it) {
        int i = tid + it * 512;
        int o = i >> 5, c4 = i & 31;
        f32x4 wv = *(const f32x4*)&w_proj[o * 128 + c4 * 4];
        unsigned int lo = (unsigned int)f2bf(wv[0]) | ((unsigned int)f2bf(wv[1]) << 16);
        unsigned int hi = (unsigned int)f2bf(wv[2]) | ((unsigned int)f2bf(wv[3]) << 16);
        u32x2 pk = {lo, hi};
        *(u32x2*)&swp[o * 128 + (((c4 >> 1) ^ (o & 7)) << 3) + (c4 & 1) * 4] = pk;
    }

    const int lane = tid & 63;
    const int l15 = lane & 15, l4 = lane >> 4;
    const int wid = tid >> 6;
    const int ntile = wid >> 1;            // freq/pixel n-tile
    const int mtbase = (wid & 1) * 4;      // channel m-tiles
    const int fcol = ntile * 16 + l15;

    // F fragments in registers (used for BOTH forward and inverse GEMMs)
    bf16x8 bre[2], bim[2];
    #pragma unroll
    for (int ks = 0; ks < 2; ++ks) {
        int cch = ks * 4 + l4;
        bre[ks] = ffrag(fcol, cch, false);
        bim[ks] = ffrag(fcol, cch, true);
    }
    __syncthreads();

    // forward GEMMs + pointwise -> ohat kept in REGISTERS (sibling waves are
    // still reading sqT/skT rows that ohr/ohi would overwrite)
    f32x4 fr_[4], fi_[4];
    #pragma unroll
    for (int mt = 0; mt < 4; ++mt) {
        const int crow = (mtbase + mt) * 16 + l15;
        bf16x8 aq[2], ak[2];
        #pragma unroll
        for (int ks = 0; ks < 2; ++ks) {
            int cch = ks * 4 + l4;
            int off = crow * 64 + ((cch ^ (crow & 7)) << 3);
            aq[ks] = *(const bf16x8*)&sqT[off];
            ak[ks] = *(const bf16x8*)&skT[off];
        }
        f32x4 qr = {0.f,0.f,0.f,0.f}, qi = qr, kr = qr, ki = qr;
        qr = __builtin_amdgcn_mfma_f32_16x16x32_bf16(aq[0], bre[0], qr, 0, 0, 0);
        qr = __builtin_amdgcn_mfma_f32_16x16x32_bf16(aq[1], bre[1], qr, 0, 0, 0);
        qi = __builtin_amdgcn_mfma_f32_16x16x32_bf16(aq[0], bim[0], qi, 0, 0, 0);
        qi = __builtin_amdgcn_mfma_f32_16x16x32_bf16(aq[1], bim[1], qi, 0, 0, 0);
        kr = __builtin_amdgcn_mfma_f32_16x16x32_bf16(ak[0], bre[0], kr, 0, 0, 0);
        kr = __builtin_amdgcn_mfma_f32_16x16x32_bf16(ak[1], bre[1], kr, 0, 0, 0);
        ki = __builtin_amdgcn_mfma_f32_16x16x32_bf16(ak[0], bim[0], ki, 0, 0, 0);
        ki = __builtin_amdgcn_mfma_f32_16x16x32_bf16(ak[1], bim[1], ki, 0, 0, 0);
        fr_[mt] = (qr * kr - qi * ki) * 0.015625f;
        fi_[mt] = (qr * ki + qi * kr) * 0.015625f;
    }
    __syncthreads();   // ALL waves done reading sqT/skT -> overlay now safe

    #pragma unroll
    for (int mt = 0; mt < 4; ++mt)
        #pragma unroll
        for (int r = 0; r < 4; ++r) {
            int c = (mtbase + mt) * 16 + l4 * 4 + r;
            int pos = c * 64 + (((fcol >> 3) ^ (c & 7)) << 3) + (fcol & 7);
            ohr[pos] = f2bf(fr_[mt][r]);
            ohi[pos] = f2bf(fi_[mt][r]);
        }
    __syncthreads();   // ohat rows complete across waves

    // inverse GEMM: out2T = ohatT_r @ Fre + ohatT_i @ Fim (B-frags = bre/bim)
    f32x4 oreg[4];
    #pragma unroll
    for (int mt = 0; mt < 4; ++mt) {
        const int crow = (mtbase + mt) * 16 + l15;
        bf16x8 ar[2], ai[2];
        #pragma unroll
        for (int ks = 0; ks < 2; ++ks) {
            int cch = ks * 4 + l4;
            int off = crow * 64 + ((cch ^ (crow & 7)) << 3);
            ar[ks] = *(const bf16x8*)&ohr[off];
            ai[ks] = *(const bf16x8*)&ohi[off];
        }
        f32x4 o2 = {0.f,0.f,0.f,0.f};
        o2 = __builtin_amdgcn_mfma_f32_16x16x32_bf16(ar[0], bre[0], o2, 0, 0, 0);
        o2 = __builtin_amdgcn_mfma_f32_16x16x32_bf16(ar[1], bre[1], o2, 0, 0, 0);
        o2 = __builtin_amdgcn_mfma_f32_16x16x32_bf16(ai[0], bim[0], o2, 0, 0, 0);
        o2 = __builtin_amdgcn_mfma_f32_16x16x32_bf16(ai[1], bim[1], o2, 0, 0, 0);
        oreg[mt] = o2;
    }
    __syncthreads();   // all ohat reads done -> out2 may overlay

    const int prow = fcol;   // pixel row for inverse output
    #pragma unroll
    for (int mt = 0; mt < 4; ++mt) {
        int c0 = (mtbase + mt) * 16 + l4 * 4;
        *(f32x4*)&out2[prow * 128 + (c0 ^ ((prow & 7) << 2))] = oreg[mt];
    }
    __syncthreads();

    // LN over 128 channels (DPP), y = LN*v, pack to sy
    const float lw0 = slw[2 * cq], lw1 = slw[2 * cq + 1];
    const float lb0 = slb[2 * cq], lb1 = slb[2 * cq + 1];
    f32x2 acc[8];
    #pragma unroll
    for (int pc = 0; pc < 8; ++pc) {
        int px = pr * 8 + pc;
        acc[pc] = *(const f32x2*)&out2[px * 128 + ((2 * cq) ^ ((px & 7) << 2))];
    }
    float mu[8], inv[8];
    #pragma unroll
    for (int pc = 0; pc < 8; ++pc) {
        float s  = wred_allsum(acc[pc].x + acc[pc].y);
        float s2 = wred_allsum(acc[pc].x * acc[pc].x + acc[pc].y * acc[pc].y);
        float m_ = s * (1.f / 128.f);
        mu[pc]  = m_;
        inv[pc] = rsqrtf(s2 * (1.f / 128.f) - m_ * m_ + 1e-5f);
    }
    __syncthreads();   // all out2 reads done -> sy may overlay

    #pragma unroll
    for (int pc = 0; pc < 8; ++pc) {
        int px = pr * 8 + pc;
        const int d = pc >> 1;
        f32x2 vp = (pc & 1) ? (f32x2){bfhi(vreg0[d]), bfhi(vreg1[d])}
                            : (f32x2){bflo(vreg0[d]), bflo(vreg1[d])};
        float y0 = ((acc[pc].x - mu[pc]) * inv[pc] * lw0 + lb0) * vp.x;
        float y1 = ((acc[pc].y - mu[pc]) * inv[pc] * lw1 + lb1) * vp.y;
        unsigned int pk = (unsigned int)f2bf(y0) | ((unsigned int)f2bf(y1) << 16);
        *(unsigned int*)&sy[px * 128 + (((cq >> 2) ^ (px & 7)) << 3) + 2 * (cq & 3)] = pk;
    }
    __syncthreads();

    // proj MFMA: [64px x 128c] x [128c x 64o]
    {
        const int mt = wid >> 1;
        const int nt0 = 2 * (wid & 1);
        f32x4 pacc[2];
        pacc[0] = (f32x4){0.f, 0.f, 0.f, 0.f};
        pacc[1] = (f32x4){0.f, 0.f, 0.f, 0.f};
        const int px_a = mt * 16 + l15;
        #pragma unroll
        for (int ks = 0; ks < 4; ++ks) {
            int cch = ks * 4 + l4;
            bf16x8 af = *(const bf16x8*)&sy[px_a * 128 + ((cch ^ (px_a & 7)) << 3)];
            #pragma unroll
            for (int p2 = 0; p2 < 2; ++p2) {
                int o_n = (nt0 + p2) * 16 + l15;
                bf16x8 bfr = *(const bf16x8*)&swp[o_n * 128 + ((cch ^ (o_n & 7)) << 3)];
                pacc[p2] = __builtin_amdgcn_mfma_f32_16x16x32_bf16(af, bfr, pacc[p2], 0, 0, 0);
            }
        }
        #pragma unroll
        for (int p2 = 0; p2 < 2; ++p2)
            #pragma unroll
            for (int r = 0; r < 4; ++r) {
                int px = mt * 16 + l4 * 4 + r;
                int o = (nt0 + p2) * 16 + l15;
                sc[px * 64 + o] = pacc[p2][r];
            }
    }
    __syncthreads();

    {
        const int o = tid & 63, r = tid >> 6;
        float v0[4], v1[4];
        #pragma unroll
        for (int j = 0; j < 4; ++j) {
            v0[j] = sc[(r * 8 + j) * 64 + o];
            v1[j] = sc[(r * 8 + 4 + j) * 64 + o];
        }
        int obase = ((b * 64 + o) * 256 + h0 + r) * 256 + w0;
        *(f32x4*)&out[obase]     = (f32x4){v0[0], v0[1], v0[2], v0[3]};
        *(f32x4*)&out[obase + 4] = (f32x4){v1[0], v1[1], v1[2], v1[3]};
    }
}

extern "C" void kernel_launch(void* const* d_in, const int* in_sizes, int n_in,
                              void* d_out, int out_size, void* d_ws, size_t ws_size,
                              hipStream_t stream) {
    (void)in_sizes; (void)n_in; (void)out_size; (void)ws_size;
    const float* x        = (const float*)d_in[0];
    const float* evt      = (const float*)d_in[1];
    const float* w_q      = (const float*)d_in[2];
    const float* w_kv     = (const float*)d_in[3];
    const float* w_qdw    = (const float*)d_in[4];
    const float* w_kvdw   = (const float*)d_in[5];
    const float* w_proj   = (const float*)d_in[6];
    const float* ln_img_w = (const float*)d_in[7];
    const float* ln_img_b = (const float*)d_in[8];
    const float* ln_evt_w = (const float*)d_in[9];
    const float* ln_evt_b = (const float*)d_in[10];
    const float* ln_out_w = (const float*)d_in[11];
    const float* ln_out_b = (const float*)d_in[12];
    float* out = (float*)d_out;

    // Workspace layout (ushorts) — proven 224 MiB footprint, nothing after vd:
    //   qd [0,64MiB) kd [64,128) eln [128,160) xln [160,192) vd=xln overlay [160,224)
    const size_t NPATCH = (size_t)4 * 32 * 32 * 8192;
    const size_t NLN    = (size_t)4 * 65536 * 64;
    unsigned short* qd  = (unsigned short*)d_ws;
    unsigned short* kd  = qd + NPATCH;
    unsigned short* eln = kd + NPATCH;
    unsigned short* xln = eln + NLN;
    unsigned short* vd  = xln;   // overlay: xln dead after prod-q; vd extends past it

    dim3 lgrid(1024, 4, 2), lblk(256);
    ln_kernel<<<lgrid, lblk, 0, stream>>>(x, evt, ln_img_w, ln_img_b,
                                          ln_evt_w, ln_evt_b, xln, eln);
    dim3 grid(32, 32, 4), blk(512);
    prod_kernel<<<grid, blk, 0, stream>>>(xln, w_q,            w_qdw,           qd);
    prod_kernel<<<grid, blk, 0, stream>>>(eln, w_kv,           w_kvdw,          kd);
    prod_kernel<<<grid, blk, 0, stream>>>(eln, w_kv + 128*64,  w_kvdw + 128*9,  vd);
    patch_kernel<<<grid, blk, 0, stream>>>(qd, kd, vd, w_proj, ln_out_w, ln_out_b, out);
}

// Round 12
// 279.614 us; speedup vs baseline: 1.1854x; 1.1854x over previous
//
#include <hip/hip_runtime.h>

typedef __attribute__((ext_vector_type(8))) short bf16x8;
typedef __attribute__((ext_vector_type(4))) float f32x4;
typedef __attribute__((ext_vector_type(2))) float f32x2;
typedef __attribute__((ext_vector_type(4))) unsigned int u32x4;
typedef __attribute__((ext_vector_type(2))) unsigned int u32x2;

__device__ __forceinline__ unsigned short f2bf(float f) {
    union { float f; unsigned int u; } v; v.f = f;
    return (unsigned short)((v.u + 0x7fffu + ((v.u >> 16) & 1u)) >> 16);
}
__device__ __forceinline__ float bflo(unsigned int u) {
    union { unsigned int u; float f; } v; v.u = u << 16; return v.f;
}
__device__ __forceinline__ float bfhi(unsigned int u) {
    union { unsigned int u; float f; } v; v.u = u & 0xffff0000u; return v.f;
}
__device__ __forceinline__ f32x2 bfpair(unsigned int u) {
    union { unsigned int u; float f; } lo, hi;
    lo.u = u << 16; hi.u = u & 0xffff0000u;
    return (f32x2){lo.f, hi.f};
}

// bf16 DFT-8 twiddles, branchless.
__device__ __forceinline__ unsigned short costab(int m) {
    unsigned short mag = (m & 1) ? 0x3F35 : (((m & 3) == 0) ? 0x3F80 : 0);
    return mag | (((m >= 3) && (m <= 5)) ? 0x8000 : 0);
}
__device__ __forceinline__ unsigned short nsintab(int m) {
    unsigned short mag = (m & 1) ? 0x3F35 : (((m & 3) == 2) ? 0x3F80 : 0);
    return mag | (((m >= 1) && (m <= 3)) ? 0x8000 : 0);
}
// F-fragment for MFMA B-operand, computed in registers (no LDS F table).
__device__ __forceinline__ bf16x8 ffrag(int fcol, int cch, bool im) {
    const int base = ((fcol >> 3) * cch) & 7;
    const int step = fcol & 7;
    union { unsigned int u[4]; bf16x8 v; } cv;
    #pragma unroll
    for (int d = 0; d < 4; ++d) {
        int m0 = (base + step * (2 * d)) & 7;
        int m1 = (base + step * (2 * d + 1)) & 7;
        unsigned short t0 = im ? nsintab(m0) : costab(m0);
        unsigned short t1 = im ? nsintab(m1) : costab(m1);
        cv.u[d] = (unsigned int)t0 | ((unsigned int)t1 << 16);
    }
    return cv.v;
}

// gfx9 64-lane all-sum via DPP (VALU pipe, not LDS pipe).
__device__ __forceinline__ float wred_allsum(float x) {
    asm volatile(
        "s_nop 1\n\t"
        "v_add_f32_dpp %0, %0, %0 row_shr:1 bound_ctrl:0\n\t"
        "s_nop 1\n\t"
        "v_add_f32_dpp %0, %0, %0 row_shr:2 bound_ctrl:0\n\t"
        "s_nop 1\n\t"
        "v_add_f32_dpp %0, %0, %0 row_shr:4 bound_ctrl:0\n\t"
        "s_nop 1\n\t"
        "v_add_f32_dpp %0, %0, %0 row_shr:8 bound_ctrl:0\n\t"
        "s_nop 1\n\t"
        "v_add_f32_dpp %0, %0, %0 row_bcast:15 row_mask:0xa bound_ctrl:0\n\t"
        "s_nop 1\n\t"
        "v_add_f32_dpp %0, %0, %0 row_bcast:31 row_mask:0xc bound_ctrl:0\n\t"
        "s_nop 1"
        : "+v"(x));
    return __builtin_bit_cast(float, __builtin_amdgcn_readlane(__builtin_bit_cast(int, x), 63));
}

// ---------------------------------------------------------------------------
// K1: channel LayerNorm, NCHW fp32 -> NHWC bf16, via LDS transpose.
// ---------------------------------------------------------------------------
__global__ __launch_bounds__(256, 8)
void ln_kernel(const float* __restrict__ x, const float* __restrict__ evt,
               const float* __restrict__ lwx, const float* __restrict__ lbx,
               const float* __restrict__ lwe, const float* __restrict__ lbe,
               unsigned short* __restrict__ xo, unsigned short* __restrict__ eo)
{
    __shared__ float xt[64][68];
    __shared__ float smu[64], sinv[64], slw[64], slb[64];

    const int tid = threadIdx.x;
    const int z = blockIdx.z, b = blockIdx.y;
    const int hw0 = blockIdx.x * 64;
    const float* src = z ? evt : x;
    const float* lw  = z ? lwe : lwx;
    const float* lb  = z ? lbe : lbx;
    unsigned short* dst = z ? eo : xo;

    if (tid < 64) { slw[tid] = lw[tid]; slb[tid] = lb[tid]; }

    const float* sp = src + (size_t)b * 64 * 65536 + hw0;
    #pragma unroll
    for (int it = 0; it < 4; ++it) {
        int i = tid + it * 256;
        int c = i >> 4, p4 = i & 15;
        f32x4 v = *(const f32x4*)&sp[(size_t)c * 65536 + p4 * 4];
        xt[p4 * 4 + 0][c] = v.x;
        xt[p4 * 4 + 1][c] = v.y;
        xt[p4 * 4 + 2][c] = v.z;
        xt[p4 * 4 + 3][c] = v.w;
    }
    __syncthreads();

    {   // stats: 4 adjacent lanes per pixel, quad shuffle-reduce
        int px = tid >> 2, part = tid & 3;
        float s = 0.f, s2 = 0.f;
        #pragma unroll
        for (int j = 0; j < 4; ++j) {
            f32x4 v = *(const f32x4*)&xt[px][part * 16 + j * 4];
            s  += v.x + v.y + v.z + v.w;
            s2 += v.x * v.x + v.y * v.y + v.z * v.z + v.w * v.w;
        }
        s  += __shfl_xor(s, 1);  s  += __shfl_xor(s, 2);
        s2 += __shfl_xor(s2, 1); s2 += __shfl_xor(s2, 2);
        if (part == 0) {
            float mu = s * (1.f / 64.f);
            smu[px] = mu;
            sinv[px] = rsqrtf(s2 * (1.f / 64.f) - mu * mu + 1e-5f);
        }
    }
    __syncthreads();

    unsigned short* dp = dst + ((size_t)b * 65536 + hw0) * 64;
    #pragma unroll
    for (int it = 0; it < 2; ++it) {
        int i = tid + it * 256;
        int px = i >> 3, oct = i & 7;
        float mu = smu[px], inv = sinv[px];
        f32x4 v0 = *(const f32x4*)&xt[px][oct * 8];
        f32x4 v1 = *(const f32x4*)&xt[px][oct * 8 + 4];
        u32x4 w;
        int c = oct * 8;
        float a0 = (v0.x - mu) * inv * slw[c + 0] + slb[c + 0];
        float a1 = (v0.y - mu) * inv * slw[c + 1] + slb[c + 1];
        w[0] = (unsigned int)f2bf(a0) | ((unsigned int)f2bf(a1) << 16);
        a0 = (v0.z - mu) * inv * slw[c + 2] + slb[c + 2];
        a1 = (v0.w - mu) * inv * slw[c + 3] + slb[c + 3];
        w[1] = (unsigned int)f2bf(a0) | ((unsigned int)f2bf(a1) << 16);
        a0 = (v1.x - mu) * inv * slw[c + 4] + slb[c + 4];
        a1 = (v1.y - mu) * inv * slw[c + 5] + slb[c + 5];
        w[2] = (unsigned int)f2bf(a0) | ((unsigned int)f2bf(a1) << 16);
        a0 = (v1.z - mu) * inv * slw[c + 6] + slb[c + 6];
        a1 = (v1.w - mu) * inv * slw[c + 7] + slb[c + 7];
        w[3] = (unsigned int)f2bf(a0) | ((unsigned int)f2bf(a1) << 16);
        *(u32x4*)&dp[(size_t)px * 64 + oct * 8] = w;
    }
}

// ---------------------------------------------------------------------------
// K2: producer (R10-proven, frozen): conv1x1 MFMA + dw3x3 + transposed blob.
// ---------------------------------------------------------------------------
#define PR_WB    14336
#define PR_WDW   30720
#define PR_SMEM  35328

__global__ __launch_bounds__(512, 8)
void prod_kernel(const unsigned short* __restrict__ src,
                 const float* __restrict__ wmat, const float* __restrict__ wdw,
                 unsigned short* __restrict__ dst)
{
    __shared__ __align__(16) char smem[PR_SMEM];
    unsigned short* A   = (unsigned short*)(smem);
    unsigned short* Wb  = (unsigned short*)(smem + PR_WB);
    unsigned short* pre = (unsigned short*)(smem);          // overlays A+Wb
    float* swdw = (float*)(smem + PR_WDW);

    const int tid = threadIdx.x;
    const int pj = blockIdx.x, pi = blockIdx.y, b = blockIdx.z;
    const int h0 = pi * 8, w0 = pj * 8;

    #pragma unroll
    for (int it = 0; it < 4; ++it) {
        int i = tid + it * 512;
        int o = i >> 4, c4 = i & 15;
        f32x4 wv = *(const f32x4*)&wmat[o * 64 + c4 * 4];
        unsigned int lo = (unsigned int)f2bf(wv[0]) | ((unsigned int)f2bf(wv[1]) << 16);
        unsigned int hi = (unsigned int)f2bf(wv[2]) | ((unsigned int)f2bf(wv[3]) << 16);
        u32x2 pk = {lo, hi};
        *(u32x2*)&Wb[o * 64 + (((c4 >> 1) ^ (o & 7)) << 3) + (c4 & 1) * 4] = pk;
    }
    for (int i = tid; i < 1152; i += 512) swdw[i] = wdw[i];
    for (int i = tid; i < 768; i += 512) A[6400 + i] = 0;
    #pragma unroll
    for (int it = 0; it < 2; ++it) {
        int i = tid + it * 512;
        if (i < 800) {
            int px = i >> 3, oct = i & 7;
            int r = px / 10, cc = px - r * 10;
            int gh = h0 - 1 + r, gw = w0 - 1 + cc;
            u32x4 val = {0u, 0u, 0u, 0u};
            if (gh >= 0 && gh < 256 && gw >= 0 && gw < 256)
                val = *(const u32x4*)&src[((size_t)(b * 65536 + gh * 256 + gw)) * 64 + oct * 8];
            *(u32x4*)&A[px * 64 + ((oct ^ (px & 7)) << 3)] = val;
        }
    }
    __syncthreads();

    const int lane = tid & 63;
    const int l15 = lane & 15, l4 = lane >> 4;
    const int o_n = (tid >> 6) * 16 + l15;
    f32x4 acc[7];
    #pragma unroll
    for (int mt = 0; mt < 7; ++mt) acc[mt] = (f32x4){0.f, 0.f, 0.f, 0.f};
    #pragma unroll
    for (int ks = 0; ks < 2; ++ks) {
        int cch = ks * 4 + l4;
        bf16x8 bfrag = *(const bf16x8*)&Wb[o_n * 64 + ((cch ^ (o_n & 7)) << 3)];
        #pragma unroll
        for (int mt = 0; mt < 7; ++mt) {
            int px = mt * 16 + l15;
            bf16x8 afrag = *(const bf16x8*)&A[px * 64 + ((cch ^ (px & 7)) << 3)];
            acc[mt] = __builtin_amdgcn_mfma_f32_16x16x32_bf16(afrag, bfrag, acc[mt], 0, 0, 0);
        }
    }
    __syncthreads();

    #pragma unroll
    for (int mt = 0; mt < 7; ++mt)
        #pragma unroll
        for (int r = 0; r < 4; ++r) {
            int px = mt * 16 + l4 * 4 + r;
            if (px < 100)
                pre[px * 128 + (((o_n >> 3) ^ (px & 7)) << 3) + (o_n & 7)] = f2bf(acc[mt][r]);
        }
    __syncthreads();

    f32x2 res[8];
    {
        const int o = (tid & 63) * 2;
        const int och = o >> 3, osub = o & 7;
        const int pc = tid >> 6;
        f32x2 wdp[9];
        #pragma unroll
        for (int t = 0; t < 9; ++t)
            wdp[t] = (f32x2){swdw[o * 9 + t], swdw[o * 9 + 9 + t]};

        f32x2 ra[3], rb[3], rc[3];
        #define LOADROW(dstv, rr)                                                        \
            {                                                                            \
                _Pragma("unroll")                                                        \
                for (int d = 0; d < 3; ++d) {                                            \
                    int hp = (rr) * 10 + pc + d;                                         \
                    unsigned int u = *(const unsigned int*)                              \
                        &pre[hp * 128 + ((och ^ (hp & 7)) << 3) + osub];                 \
                    dstv[d] = bfpair(u);                                                 \
                }                                                                        \
            }
        LOADROW(ra, 0)
        LOADROW(rb, 1)
        #pragma unroll
        for (int r = 2; r < 10; ++r) {
            LOADROW(rc, r)
            f32x2 s = ra[0] * wdp[0];
            s += ra[1] * wdp[1]; s += ra[2] * wdp[2];
            s += rb[0] * wdp[3]; s += rb[1] * wdp[4]; s += rb[2] * wdp[5];
            s += rc[0] * wdp[6]; s += rc[1] * wdp[7]; s += rc[2] * wdp[8];
            res[r - 2] = s;
            #pragma unroll
            for (int d = 0; d < 3; ++d) { ra[d] = rb[d]; rb[d] = rc[d]; }
        }
        #undef LOADROW
    }
    __syncthreads();   // pre reads done -> ldout may overlay

    {
        unsigned short* ldout = (unsigned short*)smem;
        const int o = (tid & 63) * 2;
        const int pc = tid >> 6;
        const int key = pc << 4;
        #pragma unroll
        for (int r = 0; r < 8; ++r) {
            int px = r * 8 + pc;
            unsigned int pk = (unsigned int)f2bf(res[r].x) | ((unsigned int)f2bf(res[r].y) << 16);
            *(unsigned int*)&ldout[px * 128 + (o ^ key)] = pk;
        }
    }
    __syncthreads();

    // transposed store; blob slot key = c & 7 (matches MFMA A-fragment reads)
    {
        unsigned short* ldout = (unsigned short*)smem;
        const int c0 = (tid & 63) * 2;
        const int s = tid >> 6;
        const int sl0 = s ^ (c0 & 7);
        const int sl1 = s ^ ((c0 + 1) & 7);
        const size_t patchbase = ((size_t)(b * 32 + pi) * 32 + pj) * 8192;
        unsigned int rv[8];
        #pragma unroll
        for (int j = 0; j < 8; ++j)
            rv[j] = *(const unsigned int*)&ldout[(8 * s + j) * 128 + (c0 ^ (j << 4))];
        u32x4 lo, hi;
        #pragma unroll
        for (int d = 0; d < 4; ++d) {
            lo[d] = (rv[2 * d] & 0xffffu) | (rv[2 * d + 1] << 16);
            hi[d] = (rv[2 * d] >> 16) | (rv[2 * d + 1] & 0xffff0000u);
        }
        *(u32x4*)&dst[patchbase + (size_t)c0 * 64 + sl0 * 8]       = lo;
        *(u32x4*)&dst[patchbase + (size_t)(c0 + 1) * 64 + sl1 * 8] = hi;
    }
}

// ---------------------------------------------------------------------------
// K3: patch kernel — MFMA-DFT circular conv; F frags in regs; ohat packed to
// bf16 in regs across the overlay barrier. LDS 49KB (3 blocks/CU);
// launch_bounds(512,4) so the allocator has 128 VGPRs — no spills (R11 lesson).
// ---------------------------------------------------------------------------
#define PK_R0   0
#define PK_R1   16384
#define PK_WP   32768
#define PK_LW   49152
#define PK_LB   49664
#define PK_SMEM 50176

__global__ __launch_bounds__(512, 4)
void patch_kernel(const unsigned short* __restrict__ qb,
                  const unsigned short* __restrict__ kb,
                  const unsigned short* __restrict__ vb,
                  const float* __restrict__ w_proj,
                  const float* __restrict__ lnw, const float* __restrict__ lnb,
                  float* __restrict__ out)
{
    __shared__ __align__(16) char smem[PK_SMEM];
    unsigned short* sqT  = (unsigned short*)(smem + PK_R0);
    unsigned short* skT  = (unsigned short*)(smem + PK_R1);
    unsigned short* ohr  = sqT;                      // overlay AFTER barrier
    unsigned short* ohi  = skT;
    float*          out2 = (float*)smem;             // [64p][128c] xor-swizzled
    unsigned short* swp  = (unsigned short*)(smem + PK_WP);
    unsigned short* sy   = (unsigned short*)(smem + PK_R1);  // over out2hi
    float*          sc   = (float*)(smem + PK_R0);           // over out2lo
    float* slw = (float*)(smem + PK_LW);
    float* slb = (float*)(smem + PK_LB);

    const int tid = threadIdx.x;
    const int tj = blockIdx.x, ti = blockIdx.y, b = blockIdx.z;
    const int h0 = ti * 8, w0 = tj * 8;
    const size_t pbase = ((size_t)(b * 32 + ti) * 32 + tj) * 8192;

    const int pr = tid >> 6;
    const int cq = tid & 63;

    // v prefetch from transposed blob (logical chunk pr of rows 2cq, 2cq+1)
    u32x4 vreg0 = *(const u32x4*)&vb[pbase + (2 * cq) * 64 + ((pr ^ ((2 * cq) & 7)) << 3)];
    u32x4 vreg1 = *(const u32x4*)&vb[pbase + (2 * cq + 1) * 64 + ((pr ^ ((2 * cq + 1) & 7)) << 3)];

    if (tid < 128) { slw[tid] = lnw[tid]; slb[tid] = lnb[tid]; }
    #pragma unroll
    for (int it = 0; it < 2; ++it) {
        int i = tid + it * 512;
        *(u32x4*)&sqT[i * 8] = *(const u32x4*)&qb[pbase + i * 8];
        *(u32x4*)&skT[i * 8] = *(const u32x4*)&kb[pbase + i * 8];
    }
    #pragma unroll
    for (int it = 0; it < 4; ++it) {
        int i = tid + it * 512;
        int o = i >> 5, c4 = i & 31;
        f32x4 wv = *(const f32x4*)&w_proj[o * 128 + c4 * 4];
        unsigned int lo = (unsigned int)f2bf(wv[0]) | ((unsigned int)f2bf(wv[1]) << 16);
        unsigned int hi = (unsigned int)f2bf(wv[2]) | ((unsigned int)f2bf(wv[3]) << 16);
        u32x2 pk = {lo, hi};
        *(u32x2*)&swp[o * 128 + (((c4 >> 1) ^ (o & 7)) << 3) + (c4 & 1) * 4] = pk;
    }

    const int lane = tid & 63;
    const int l15 = lane & 15, l4 = lane >> 4;
    const int wid = tid >> 6;
    const int ntile = wid >> 1;            // freq/pixel n-tile
    const int mtbase = (wid & 1) * 4;      // channel m-tiles
    const int fcol = ntile * 16 + l15;

    // F fragments in registers (used for BOTH forward and inverse GEMMs)
    bf16x8 bre[2], bim[2];
    #pragma unroll
    for (int ks = 0; ks < 2; ++ks) {
        int cch = ks * 4 + l4;
        bre[ks] = ffrag(fcol, cch, false);
        bim[ks] = ffrag(fcol, cch, true);
    }
    __syncthreads();

    // forward GEMMs + pointwise -> ohat PACKED bf16 in regs (16 VGPRs, not 32)
    u32x2 opr[4], opi[4];
    #pragma unroll
    for (int mt = 0; mt < 4; ++mt) {
        const int crow = (mtbase + mt) * 16 + l15;
        bf16x8 aq[2], ak[2];
        #pragma unroll
        for (int ks = 0; ks < 2; ++ks) {
            int cch = ks * 4 + l4;
            int off = crow * 64 + ((cch ^ (crow & 7)) << 3);
            aq[ks] = *(const bf16x8*)&sqT[off];
            ak[ks] = *(const bf16x8*)&skT[off];
        }
        f32x4 qr = {0.f,0.f,0.f,0.f}, qi = qr, kr = qr, ki = qr;
        qr = __builtin_amdgcn_mfma_f32_16x16x32_bf16(aq[0], bre[0], qr, 0, 0, 0);
        qr = __builtin_amdgcn_mfma_f32_16x16x32_bf16(aq[1], bre[1], qr, 0, 0, 0);
        qi = __builtin_amdgcn_mfma_f32_16x16x32_bf16(aq[0], bim[0], qi, 0, 0, 0);
        qi = __builtin_amdgcn_mfma_f32_16x16x32_bf16(aq[1], bim[1], qi, 0, 0, 0);
        kr = __builtin_amdgcn_mfma_f32_16x16x32_bf16(ak[0], bre[0], kr, 0, 0, 0);
        kr = __builtin_amdgcn_mfma_f32_16x16x32_bf16(ak[1], bre[1], kr, 0, 0, 0);
        ki = __builtin_amdgcn_mfma_f32_16x16x32_bf16(ak[0], bim[0], ki, 0, 0, 0);
        ki = __builtin_amdgcn_mfma_f32_16x16x32_bf16(ak[1], bim[1], ki, 0, 0, 0);
        f32x4 fr = (qr * kr - qi * ki) * 0.015625f;
        f32x4 fi = (qr * ki + qi * kr) * 0.015625f;
        opr[mt] = (u32x2){
            (unsigned int)f2bf(fr[0]) | ((unsigned int)f2bf(fr[1]) << 16),
            (unsigned int)f2bf(fr[2]) | ((unsigned int)f2bf(fr[3]) << 16)};
        opi[mt] = (u32x2){
            (unsigned int)f2bf(fi[0]) | ((unsigned int)f2bf(fi[1]) << 16),
            (unsigned int)f2bf(fi[2]) | ((unsigned int)f2bf(fi[3]) << 16)};
    }
    __syncthreads();   // ALL waves done reading sqT/skT -> overlay now safe

    #pragma unroll
    for (int mt = 0; mt < 4; ++mt)
        #pragma unroll
        for (int r = 0; r < 4; ++r) {
            int c = (mtbase + mt) * 16 + l4 * 4 + r;
            int pos = c * 64 + (((fcol >> 3) ^ (c & 7)) << 3) + (fcol & 7);
            unsigned int wr = opr[mt][r >> 1], wi = opi[mt][r >> 1];
            ohr[pos] = (r & 1) ? (unsigned short)(wr >> 16) : (unsigned short)(wr & 0xffffu);
            ohi[pos] = (r & 1) ? (unsigned short)(wi >> 16) : (unsigned short)(wi & 0xffffu);
        }
    __syncthreads();   // ohat rows complete across waves

    // inverse GEMM: out2T = ohatT_r @ Fre + ohatT_i @ Fim (B-frags = bre/bim)
    f32x4 oreg[4];
    #pragma unroll
    for (int mt = 0; mt < 4; ++mt) {
        const int crow = (mtbase + mt) * 16 + l15;
        bf16x8 ar[2], ai[2];
        #pragma unroll
        for (int ks = 0; ks < 2; ++ks) {
            int cch = ks * 4 + l4;
            int off = crow * 64 + ((cch ^ (crow & 7)) << 3);
            ar[ks] = *(const bf16x8*)&ohr[off];
            ai[ks] = *(const bf16x8*)&ohi[off];
        }
        f32x4 o2 = {0.f,0.f,0.f,0.f};
        o2 = __builtin_amdgcn_mfma_f32_16x16x32_bf16(ar[0], bre[0], o2, 0, 0, 0);
        o2 = __builtin_amdgcn_mfma_f32_16x16x32_bf16(ar[1], bre[1], o2, 0, 0, 0);
        o2 = __builtin_amdgcn_mfma_f32_16x16x32_bf16(ai[0], bim[0], o2, 0, 0, 0);
        o2 = __builtin_amdgcn_mfma_f32_16x16x32_bf16(ai[1], bim[1], o2, 0, 0, 0);
        oreg[mt] = o2;
    }
    __syncthreads();   // all ohat reads done -> out2 may overlay

    const int prow = fcol;   // pixel row for inverse output
    #pragma unroll
    for (int mt = 0; mt < 4; ++mt) {
        int c0 = (mtbase + mt) * 16 + l4 * 4;
        *(f32x4*)&out2[prow * 128 + (c0 ^ ((prow & 7) << 2))] = oreg[mt];
    }
    __syncthreads();

    // LN over 128 channels (DPP), y = LN*v, pack to sy
    const float lw0 = slw[2 * cq], lw1 = slw[2 * cq + 1];
    const float lb0 = slb[2 * cq], lb1 = slb[2 * cq + 1];
    f32x2 acc[8];
    #pragma unroll
    for (int pc = 0; pc < 8; ++pc) {
        int px = pr * 8 + pc;
        acc[pc] = *(const f32x2*)&out2[px * 128 + ((2 * cq) ^ ((px & 7) << 2))];
    }
    float mu[8], inv[8];
    #pragma unroll
    for (int pc = 0; pc < 8; ++pc) {
        float s  = wred_allsum(acc[pc].x + acc[pc].y);
        float s2 = wred_allsum(acc[pc].x * acc[pc].x + acc[pc].y * acc[pc].y);
        float m_ = s * (1.f / 128.f);
        mu[pc]  = m_;
        inv[pc] = rsqrtf(s2 * (1.f / 128.f) - m_ * m_ + 1e-5f);
    }
    __syncthreads();   // all out2 reads done -> sy may overlay

    #pragma unroll
    for (int pc = 0; pc < 8; ++pc) {
        int px = pr * 8 + pc;
        const int d = pc >> 1;
        f32x2 vp = (pc & 1) ? (f32x2){bfhi(vreg0[d]), bfhi(vreg1[d])}
                            : (f32x2){bflo(vreg0[d]), bflo(vreg1[d])};
        float y0 = ((acc[pc].x - mu[pc]) * inv[pc] * lw0 + lb0) * vp.x;
        float y1 = ((acc[pc].y - mu[pc]) * inv[pc] * lw1 + lb1) * vp.y;
        unsigned int pk = (unsigned int)f2bf(y0) | ((unsigned int)f2bf(y1) << 16);
        *(unsigned int*)&sy[px * 128 + (((cq >> 2) ^ (px & 7)) << 3) + 2 * (cq & 3)] = pk;
    }
    __syncthreads();

    // proj MFMA: [64px x 128c] x [128c x 64o]
    {
        const int mt = wid >> 1;
        const int nt0 = 2 * (wid & 1);
        f32x4 pacc[2];
        pacc[0] = (f32x4){0.f, 0.f, 0.f, 0.f};
        pacc[1] = (f32x4){0.f, 0.f, 0.f, 0.f};
        const int px_a = mt * 16 + l15;
        #pragma unroll
        for (int ks = 0; ks < 4; ++ks) {
            int cch = ks * 4 + l4;
            bf16x8 af = *(const bf16x8*)&sy[px_a * 128 + ((cch ^ (px_a & 7)) << 3)];
            #pragma unroll
            for (int p2 = 0; p2 < 2; ++p2) {
                int o_n = (nt0 + p2) * 16 + l15;
                bf16x8 bfr = *(const bf16x8*)&swp[o_n * 128 + ((cch ^ (o_n & 7)) << 3)];
                pacc[p2] = __builtin_amdgcn_mfma_f32_16x16x32_bf16(af, bfr, pacc[p2], 0, 0, 0);
            }
        }
        #pragma unroll
        for (int p2 = 0; p2 < 2; ++p2)
            #pragma unroll
            for (int r = 0; r < 4; ++r) {
                int px = mt * 16 + l4 * 4 + r;
                int o = (nt0 + p2) * 16 + l15;
                sc[px * 64 + o] = pacc[p2][r];
            }
    }
    __syncthreads();

    {
        const int o = tid & 63, r = tid >> 6;
        float v0[4], v1[4];
        #pragma unroll
        for (int j = 0; j < 4; ++j) {
            v0[j] = sc[(r * 8 + j) * 64 + o];
            v1[j] = sc[(r * 8 + 4 + j) * 64 + o];
        }
        int obase = ((b * 64 + o) * 256 + h0 + r) * 256 + w0;
        *(f32x4*)&out[obase]     = (f32x4){v0[0], v0[1], v0[2], v0[3]};
        *(f32x4*)&out[obase + 4] = (f32x4){v1[0], v1[1], v1[2], v1[3]};
    }
}

extern "C" void kernel_launch(void* const* d_in, const int* in_sizes, int n_in,
                              void* d_out, int out_size, void* d_ws, size_t ws_size,
                              hipStream_t stream) {
    (void)in_sizes; (void)n_in; (void)out_size; (void)ws_size;
    const float* x        = (const float*)d_in[0];
    const float* evt      = (const float*)d_in[1];
    const float* w_q      = (const float*)d_in[2];
    const float* w_kv     = (const float*)d_in[3];
    const float* w_qdw    = (const float*)d_in[4];
    const float* w_kvdw   = (const float*)d_in[5];
    const float* w_proj   = (const float*)d_in[6];
    const float* ln_img_w = (const float*)d_in[7];
    const float* ln_img_b = (const float*)d_in[8];
    const float* ln_evt_w = (const float*)d_in[9];
    const float* ln_evt_b = (const float*)d_in[10];
    const float* ln_out_w = (const float*)d_in[11];
    const float* ln_out_b = (const float*)d_in[12];
    float* out = (float*)d_out;

    // Workspace layout (ushorts) — proven 224 MiB footprint, nothing after vd:
    //   qd [0,64MiB) kd [64,128) eln [128,160) xln [160,192) vd=xln overlay [160,224)
    const size_t NPATCH = (size_t)4 * 32 * 32 * 8192;
    const size_t NLN    = (size_t)4 * 65536 * 64;
    unsigned short* qd  = (unsigned short*)d_ws;
    unsigned short* kd  = qd + NPATCH;
    unsigned short* eln = kd + NPATCH;
    unsigned short* xln = eln + NLN;
    unsigned short* vd  = xln;   // overlay: xln dead after prod-q; vd extends past it

    dim3 lgrid(1024, 4, 2), lblk(256);
    ln_kernel<<<lgrid, lblk, 0, stream>>>(x, evt, ln_img_w, ln_img_b,
                                          ln_evt_w, ln_evt_b, xln, eln);
    dim3 grid(32, 32, 4), blk(512);
    prod_kernel<<<grid, blk, 0, stream>>>(xln, w_q,            w_qdw,           qd);
    prod_kernel<<<grid, blk, 0, stream>>>(eln, w_kv,           w_kvdw,          kd);
    prod_kernel<<<grid, blk, 0, stream>>>(eln, w_kv + 128*64,  w_kvdw + 128*9,  vd);
    patch_kernel<<<grid, blk, 0, stream>>>(qd, kd, vd, w_proj, ln_out_w, ln_out_b, out);
}